// Round 1
// baseline (14924.399 us; speedup 1.0000x reference)
//
#include <hip/hip_runtime.h>
#include <stdint.h>

typedef unsigned short u16;
typedef unsigned int u32;
typedef unsigned long long u64;

#define Hdim 512
#define Ddim 300
#define Tlen 1024
#define VG 40000
#define VS 25000
#define NGTOT (Tlen * VG)          // 40,960,000
#define NTOT  (Tlen * (VG + VS))   // 66,560,000

// ---- workspace layout (in floats) ----
#define O_XZ   0
#define O_XR   (O_XZ + Tlen * Hdim)          //  524288
#define O_X1   (O_XR + Tlen * Hdim)
#define O_H1   (O_X1 + Tlen * Hdim)          // h1seq [1025][512]
#define O_H2   (O_H1 + (Tlen + 1) * Hdim)    // h2seq [1025][512]
#define O_R1   (O_H2 + (Tlen + 1) * Hdim)
#define O_R2   (O_R1 + Tlen * Hdim)
#define O_HBF  (O_R2 + Tlen * Hdim)          // u16[1024*512] = 262144 floats
#define O_WGBF (O_HBF + (Tlen * Hdim) / 2)   // u16[512*40000] = 10,240,000 floats
#define O_WSBF (O_WGBF + (Hdim * VG) / 2)    // u16[512*25000] = 6,400,000 floats
#define O_PG   (O_WSBF + (Hdim * VS) / 2)    // [1024][625]
#define O_PS   (O_PG + Tlen * 625)           // [1024][391]
#define O_LSE  (O_PS + Tlen * 391)           // [2048]
#define O_CNT  (O_LSE + 2048)                // int[256]

__device__ __forceinline__ u16 f2bf(float f) {
    u32 u = __float_as_uint(f);
    u += 0x7fffu + ((u >> 16) & 1u);
    return (u16)(u >> 16);
}
__device__ __forceinline__ float bf2f(u16 s) { return __uint_as_float(((u32)s) << 16); }
__device__ __forceinline__ float sigm(float x) { return 1.f / (1.f + __expf(-x)); }

__device__ __forceinline__ float ldg_f(const float* p) {
    return __hip_atomic_load(p, __ATOMIC_RELAXED, __HIP_MEMORY_SCOPE_AGENT);
}
__device__ __forceinline__ void stg_f(float* p, float v) {
    __hip_atomic_store(p, v, __ATOMIC_RELAXED, __HIP_MEMORY_SCOPE_AGENT);
}
__device__ __forceinline__ int ldg_i(const int* p) {
    return __hip_atomic_load(p, __ATOMIC_RELAXED, __HIP_MEMORY_SCOPE_AGENT);
}
__device__ __forceinline__ void st_rel_i(int* p, int v) {
    __hip_atomic_store(p, v, __ATOMIC_RELEASE, __HIP_MEMORY_SCOPE_AGENT);
}

// ---------------- init: zero recurrent seeds + flags ----------------
__global__ void k_init(float* h1seq, float* h2seq, int* cnt) {
    int i = blockIdx.x * 256 + threadIdx.x;
    if (i < Hdim) { h1seq[i] = 0.f; h2seq[i] = 0.f; }
    if (i < 256) cnt[i] = 0;
}

// ---------------- x-projections: x_emb @ {Wz1,Wr1,W1} ----------------
__launch_bounds__(256)
__global__ void k_xproj(const int* tokens, const float* X,
                        const float* Wz1, const float* Wr1, const float* W1,
                        float* xz, float* xr, float* x1) {
    int tid = threadIdx.x;
    int jj = tid & 63, tg = tid >> 6;
    int mat = blockIdx.y >> 3;
    int j0 = (blockIdx.y & 7) * 64;
    int t0 = blockIdx.x * 16 + tg * 4;
    const float* W = (mat == 0) ? Wz1 : (mat == 1 ? Wr1 : W1);
    float* out = (mat == 0) ? xz : (mat == 1 ? xr : x1);
    const float* xrow[4];
#pragma unroll
    for (int u = 0; u < 4; ++u) xrow[u] = X + (size_t)tokens[t0 + u] * Ddim;
    float acc[4] = {0.f, 0.f, 0.f, 0.f};
    for (int k = 0; k < Ddim; ++k) {
        float w = W[(size_t)k * Hdim + j0 + jj];
#pragma unroll
        for (int u = 0; u < 4; ++u) acc[u] += xrow[u][k] * w;
    }
#pragma unroll
    for (int u = 0; u < 4; ++u) out[(size_t)(t0 + u) * Hdim + j0 + jj] = acc[u];
}

// ---------------- vocab weight fp32 -> bf16 ----------------
__global__ void k_wconv(const float* Wg, const float* Ws, u16* wgbf, u16* wsbf) {
    const int n4g = (Hdim * VG) / 4;             // packs of 4 elems
    const int n4s = (Hdim * VS) / 4;
    int stride = gridDim.x * blockDim.x;
    for (int i = blockIdx.x * blockDim.x + threadIdx.x; i < n4g + n4s; i += stride) {
        float4 v;
        u64* dst;
        if (i < n4g) { v = ((const float4*)Wg)[i]; dst = (u64*)wgbf + i; }
        else { int j = i - n4g; v = ((const float4*)Ws)[j]; dst = (u64*)wsbf + j; }
        u64 p = (u64)f2bf(v.x) | ((u64)f2bf(v.y) << 16) | ((u64)f2bf(v.z) << 32) | ((u64)f2bf(v.w) << 48);
        *dst = p;
    }
}

// ---------------- h2s fp32 -> bf16 (A matrix for GEMM) ----------------
__global__ void k_hbf(const float* h2seq, u16* hbf) {
    int i = blockIdx.x * 256 + threadIdx.x;   // grid 2048 x 256 == 524288
    hbf[i] = f2bf(h2seq[i + Hdim]);           // h2s[t] = h2seq[t+1]
}

// ---------------- sequential GRU scan: 96 persistent WGs ----------------
#define G1n 32
#define C1n 16
#define G2n 64
#define C2n 8

__launch_bounds__(256)
__global__ void k_scan(const float* Uz1, const float* Ur1, const float* U1,
                       const float* Wz2, const float* Uz2, const float* Wr2,
                       const float* Ur2, const float* W2, const float* U2,
                       const float* xz, const float* xr, const float* x1,
                       float* h1seq, float* h2seq, float* r1buf, float* r2buf,
                       int* cnt) {
    __shared__ u16 wsl[24576];           // 48 KB weight slices (bf16)
    __shared__ float hA[Hdim], hB[Hdim], hC[Hdim];
    int tid = threadIdx.x, lane = tid & 63;
    int g = blockIdx.x;
    int* cnt_h1 = cnt;
    int* cnt_r1 = cnt + 32;
    int* cnt_h2 = cnt + 64;
    int* cnt_r2 = cnt + 128;

    if (g < G1n) {
        // ---------------- layer 1 ----------------
        int c0 = g * C1n;
        const float* Us[3] = {Uz1, Ur1, U1};
        for (int m = 0; m < 3; ++m) {
            for (int k = 0; k < 2; ++k) {
                int i = tid + k * 256;
                const float* src = Us[m] + (size_t)i * Hdim + c0;
                float v[16];
#pragma unroll
                for (int q = 0; q < 4; ++q) {
                    float4 f = ((const float4*)src)[q];
                    v[q * 4] = f.x; v[q * 4 + 1] = f.y; v[q * 4 + 2] = f.z; v[q * 4 + 3] = f.w;
                }
#pragma unroll
                for (int cc = 0; cc < 16; ++cc) wsl[(m * C1n + cc) * Hdim + i] = f2bf(v[cc]);
            }
        }
        __syncthreads();
        int c = tid >> 4, r = tid & 15;
        int i0 = r * 32;
        const u16* wz = &wsl[(0 * C1n + c) * Hdim];
        const u16* wr = &wsl[(1 * C1n + c) * Hdim];
        const u16* w1 = &wsl[(2 * C1n + c) * Hdim];
        for (int t = 0; t < Tlen; ++t) {
            if (t > 0) {
                while (1) {
                    int v = (lane < G1n) ? ldg_i(&cnt_h1[lane]) : t;
                    if (__all(v >= t)) break;
                    __builtin_amdgcn_s_sleep(1);
                }
                __builtin_amdgcn_fence(__ATOMIC_ACQUIRE, "agent");
            }
            hA[tid] = ldg_f(&h1seq[t * Hdim + tid]);
            hA[tid + 256] = ldg_f(&h1seq[t * Hdim + tid + 256]);
            __syncthreads();
            // stage 1: z1, r1
            float az = 0.f, ar = 0.f;
#pragma unroll 8
            for (int ii = 0; ii < 32; ++ii) {
                int i = i0 + ii;
                float h = hA[i];
                az += h * bf2f(wz[i]);
                ar += h * bf2f(wr[i]);
            }
#pragma unroll
            for (int d = 8; d; d >>= 1) { az += __shfl_down(az, d, 16); ar += __shfl_down(ar, d, 16); }
            float zg = 0.f;
            if (r == 0) {
                float xzv = xz[t * Hdim + c0 + c];
                float xrv = xr[t * Hdim + c0 + c];
                zg = sigm(az + xzv);
                float rg = sigm(ar + xrv);
                stg_f(&r1buf[t * Hdim + c0 + c], rg);
            }
            __syncthreads();
            if (tid == 0) st_rel_i(&cnt_r1[g], t + 1);
            while (1) {
                int v = (lane < G1n) ? ldg_i(&cnt_r1[lane]) : (t + 1);
                if (__all(v >= t + 1)) break;
                __builtin_amdgcn_s_sleep(1);
            }
            __builtin_amdgcn_fence(__ATOMIC_ACQUIRE, "agent");
            hB[tid] = ldg_f(&r1buf[t * Hdim + tid]);
            hB[tid + 256] = ldg_f(&r1buf[t * Hdim + tid + 256]);
            __syncthreads();
            // stage 2: ht1, h1n
            float a = 0.f;
#pragma unroll 8
            for (int ii = 0; ii < 32; ++ii) {
                int i = i0 + ii;
                a += hB[i] * hA[i] * bf2f(w1[i]);
            }
#pragma unroll
            for (int d = 8; d; d >>= 1) a += __shfl_down(a, d, 16);
            if (r == 0) {
                float x1v = x1[t * Hdim + c0 + c];
                float ht = tanhf(a + x1v);
                float hn = zg * ht + (1.f - zg) * hA[c0 + c];
                stg_f(&h1seq[(t + 1) * Hdim + c0 + c], hn);
            }
            __syncthreads();
            if (tid == 0) st_rel_i(&cnt_h1[g], t + 1);
        }
    } else {
        // ---------------- layer 2 ----------------
        int g2 = g - G1n, c0 = g2 * C2n;
        const float* Us[6] = {Wz2, Uz2, Wr2, Ur2, W2, U2};
        for (int m = 0; m < 6; ++m) {
            for (int k = 0; k < 2; ++k) {
                int i = tid + k * 256;
                const float* src = Us[m] + (size_t)i * Hdim + c0;
                float v[8];
#pragma unroll
                for (int q = 0; q < 2; ++q) {
                    float4 f = ((const float4*)src)[q];
                    v[q * 4] = f.x; v[q * 4 + 1] = f.y; v[q * 4 + 2] = f.z; v[q * 4 + 3] = f.w;
                }
#pragma unroll
                for (int cc = 0; cc < 8; ++cc) wsl[(m * C2n + cc) * Hdim + i] = f2bf(v[cc]);
            }
        }
        __syncthreads();
        int c = tid >> 5, r = tid & 31;
        int i0 = r * 16;
        const u16* w0 = &wsl[(0 * C2n + c) * Hdim];
        const u16* w1p = &wsl[(1 * C2n + c) * Hdim];
        const u16* w2p = &wsl[(2 * C2n + c) * Hdim];
        const u16* w3p = &wsl[(3 * C2n + c) * Hdim];
        const u16* w4p = &wsl[(4 * C2n + c) * Hdim];
        const u16* w5p = &wsl[(5 * C2n + c) * Hdim];
        for (int t = 0; t < Tlen; ++t) {
            while (1) {
                int v1 = (lane < G1n) ? ldg_i(&cnt_h1[lane]) : (t + 1);
                int v2 = ldg_i(&cnt_h2[lane]);
                if (__all((v1 >= t + 1) && (v2 >= t))) break;
                __builtin_amdgcn_s_sleep(1);
            }
            __builtin_amdgcn_fence(__ATOMIC_ACQUIRE, "agent");
            hA[tid] = ldg_f(&h1seq[(t + 1) * Hdim + tid]);
            hA[tid + 256] = ldg_f(&h1seq[(t + 1) * Hdim + tid + 256]);
            hB[tid] = ldg_f(&h2seq[t * Hdim + tid]);
            hB[tid + 256] = ldg_f(&h2seq[t * Hdim + tid + 256]);
            __syncthreads();
            // stage 3: z2, r2
            float az = 0.f, ar = 0.f;
#pragma unroll 8
            for (int ii = 0; ii < 16; ++ii) {
                int i = i0 + ii;
                float a_ = hA[i], b_ = hB[i];
                az += a_ * bf2f(w0[i]) + b_ * bf2f(w1p[i]);
                ar += a_ * bf2f(w2p[i]) + b_ * bf2f(w3p[i]);
            }
#pragma unroll
            for (int d = 16; d; d >>= 1) { az += __shfl_down(az, d, 32); ar += __shfl_down(ar, d, 32); }
            float zg = 0.f;
            if (r == 0) {
                zg = sigm(az);
                float rg = sigm(ar);
                stg_f(&r2buf[t * Hdim + c0 + c], rg);
            }
            __syncthreads();
            if (tid == 0) st_rel_i(&cnt_r2[g2], t + 1);
            while (1) {
                int v = ldg_i(&cnt_r2[lane]);
                if (__all(v >= t + 1)) break;
                __builtin_amdgcn_s_sleep(1);
            }
            __builtin_amdgcn_fence(__ATOMIC_ACQUIRE, "agent");
            hC[tid] = ldg_f(&r2buf[t * Hdim + tid]);
            hC[tid + 256] = ldg_f(&r2buf[t * Hdim + tid + 256]);
            __syncthreads();
            // stage 4: ht2, h2n
            float a = 0.f;
#pragma unroll 8
            for (int ii = 0; ii < 16; ++ii) {
                int i = i0 + ii;
                a += hA[i] * bf2f(w4p[i]) + hC[i] * hB[i] * bf2f(w5p[i]);
            }
#pragma unroll
            for (int d = 16; d; d >>= 1) a += __shfl_down(a, d, 32);
            if (r == 0) {
                float ht = tanhf(a);
                float hn = zg * ht + (1.f - zg) * hB[c0 + c];
                stg_f(&h2seq[(t + 1) * Hdim + c0 + c], hn);
            }
            __syncthreads();
            if (tid == 0) st_rel_i(&cnt_h2[g2], t + 1);
        }
    }
}

// ---------------- bf16 MFMA GEMM: logits + per-block sumexp partials ----------------
typedef __attribute__((ext_vector_type(8))) short bfrag;
typedef __attribute__((ext_vector_type(4))) float f32x4;

__launch_bounds__(256)
__global__ void k_gemm(const u16* A, const u16* B, const float* bias,
                       float* out, float* partial, int N, int nblk) {
    __shared__ u16 As[64 * 40];
    __shared__ u16 Bs[64 * 40];
    int tid = threadIdx.x, lane = tid & 63, wid = tid >> 6;
    int m0 = blockIdx.x * 64, n0 = blockIdx.y * 64;
    f32x4 acc[4] = {{0.f, 0.f, 0.f, 0.f}, {0.f, 0.f, 0.f, 0.f}, {0.f, 0.f, 0.f, 0.f}, {0.f, 0.f, 0.f, 0.f}};
    int arow = tid >> 2, akc = (tid & 3) * 8;
    int bkr = tid >> 3, bnc = (tid & 7) * 8;
    bool bvalid = (n0 + bnc) < N;   // chunks are fully valid or invalid (N % 8 == 0)
    int lm = lane & 15, q = lane >> 4;
    for (int kt = 0; kt < 16; ++kt) {
        int k0 = kt * 32;
        uint4 av = *(const uint4*)(A + (size_t)(m0 + arow) * Hdim + k0 + akc);
        *((uint4*)&As[arow * 40 + akc]) = av;
        union { uint4 v; u16 s[8]; } ub;
        ub.v = make_uint4(0, 0, 0, 0);
        if (bvalid) ub.v = *(const uint4*)(B + (size_t)(k0 + bkr) * N + n0 + bnc);
#pragma unroll
        for (int j = 0; j < 8; ++j) Bs[(bnc + j) * 40 + bkr] = ub.s[j];
        __syncthreads();
        bfrag af = *(const bfrag*)&As[(wid * 16 + lm) * 40 + q * 8];
#pragma unroll
        for (int ns = 0; ns < 4; ++ns) {
            bfrag bf_ = *(const bfrag*)&Bs[(ns * 16 + lm) * 40 + q * 8];
            acc[ns] = __builtin_amdgcn_mfma_f32_16x16x32_bf16(af, bf_, acc[ns], 0, 0, 0);
        }
        __syncthreads();
    }
    // epilogue: store logits (+bias) and accumulate per-row sum(exp)
    float rs[4] = {0.f, 0.f, 0.f, 0.f};
#pragma unroll
    for (int ns = 0; ns < 4; ++ns) {
        int col = n0 + ns * 16 + lm;
        bool cv = col < N;
        float bi = cv ? bias[col] : 0.f;
#pragma unroll
        for (int rr = 0; rr < 4; ++rr) {
            int row = wid * 16 + q * 4 + rr;
            float v = acc[ns][rr] + bi;
            if (cv) {
                out[(size_t)(m0 + row) * N + col] = v;
                rs[rr] += __expf(v);
            }
        }
    }
#pragma unroll
    for (int rr = 0; rr < 4; ++rr) {
#pragma unroll
        for (int d = 1; d < 16; d <<= 1) rs[rr] += __shfl_xor(rs[rr], d, 64);
    }
    if (lm == 0) {
#pragma unroll
        for (int rr = 0; rr < 4; ++rr) {
            int row = wid * 16 + q * 4 + rr;
            partial[(size_t)(m0 + row) * nblk + blockIdx.y] = rs[rr];
        }
    }
}

// ---------------- per-row logsumexp reduce ----------------
__global__ void k_lse(const float* pG, const float* pS, float* lse) {
    int row = blockIdx.x;        // 0..2047
    int tid = threadIdx.x;
    const float* p;
    int nb;
    if (row < Tlen) { p = pG + (size_t)row * 625; nb = 625; }
    else { p = pS + (size_t)(row - Tlen) * 391; nb = 391; }
    float s = 0.f;
    for (int j = tid; j < nb; j += 256) s += p[j];
#pragma unroll
    for (int d = 32; d; d >>= 1) s += __shfl_down(s, d, 64);
    __shared__ float red[4];
    if ((tid & 63) == 0) red[tid >> 6] = s;
    __syncthreads();
    if (tid == 0) lse[row] = logf(red[0] + red[1] + red[2] + red[3]);
}

// ---------------- in-place fixup: out -= lse[row] ----------------
__global__ void k_fix(float* out, const float* lse) {
    const size_t n4 = NTOT / 4;
    size_t stride = (size_t)gridDim.x * blockDim.x;
    for (size_t i = (size_t)blockIdx.x * blockDim.x + threadIdx.x; i < n4; i += stride) {
        size_t e = i * 4;
        float l;
        if (e < (size_t)NGTOT) l = lse[e / VG];
        else l = lse[Tlen + (e - (size_t)NGTOT) / VS];
        float4 v = ((float4*)out)[i];
        v.x -= l; v.y -= l; v.z -= l; v.w -= l;
        ((float4*)out)[i] = v;
    }
}

extern "C" void kernel_launch(void* const* d_in, const int* in_sizes, int n_in,
                              void* d_out, int out_size, void* d_ws, size_t ws_size,
                              hipStream_t stream) {
    const int* tokens = (const int*)d_in[0];
    const float* X   = (const float*)d_in[1];
    const float* Wz1 = (const float*)d_in[2];
    const float* Uz1 = (const float*)d_in[3];
    const float* Wr1 = (const float*)d_in[4];
    const float* Ur1 = (const float*)d_in[5];
    const float* W1  = (const float*)d_in[6];
    const float* U1  = (const float*)d_in[7];
    const float* Wz2 = (const float*)d_in[8];
    const float* Uz2 = (const float*)d_in[9];
    const float* Wr2 = (const float*)d_in[10];
    const float* Ur2 = (const float*)d_in[11];
    const float* W2  = (const float*)d_in[12];
    const float* U2  = (const float*)d_in[13];
    const float* Wg  = (const float*)d_in[14];
    const float* bg  = (const float*)d_in[15];
    const float* Ws  = (const float*)d_in[16];
    const float* bs  = (const float*)d_in[17];

    float* wsf = (float*)d_ws;
    float* xz = wsf + O_XZ;
    float* xr = wsf + O_XR;
    float* x1 = wsf + O_X1;
    float* h1seq = wsf + O_H1;
    float* h2seq = wsf + O_H2;
    float* r1buf = wsf + O_R1;
    float* r2buf = wsf + O_R2;
    u16* hbf  = (u16*)(wsf + O_HBF);
    u16* wgbf = (u16*)(wsf + O_WGBF);
    u16* wsbf = (u16*)(wsf + O_WSBF);
    float* pG = wsf + O_PG;
    float* pS = wsf + O_PS;
    float* lse = wsf + O_LSE;
    int* cnt = (int*)(wsf + O_CNT);
    float* outF = (float*)d_out;

    hipLaunchKernelGGL(k_init, dim3(2), dim3(256), 0, stream, h1seq, h2seq, cnt);
    hipLaunchKernelGGL(k_xproj, dim3(64, 24), dim3(256), 0, stream,
                       tokens, X, Wz1, Wr1, W1, xz, xr, x1);
    hipLaunchKernelGGL(k_wconv, dim3(4096), dim3(256), 0, stream, Wg, Ws, wgbf, wsbf);
    hipLaunchKernelGGL(k_scan, dim3(96), dim3(256), 0, stream,
                       Uz1, Ur1, U1, Wz2, Uz2, Wr2, Ur2, W2, U2,
                       xz, xr, x1, h1seq, h2seq, r1buf, r2buf, cnt);
    hipLaunchKernelGGL(k_hbf, dim3(2048), dim3(256), 0, stream, h2seq, hbf);
    hipLaunchKernelGGL(k_gemm, dim3(16, 625), dim3(256), 0, stream,
                       hbf, wgbf, bg, outF, pG, VG, 625);
    hipLaunchKernelGGL(k_gemm, dim3(16, 391), dim3(256), 0, stream,
                       hbf, wsbf, bs, outF + (size_t)NGTOT, pS, VS, 391);
    hipLaunchKernelGGL(k_lse, dim3(2048), dim3(256), 0, stream, pG, pS, lse);
    hipLaunchKernelGGL(k_fix, dim3(8192), dim3(256), 0, stream, outF, lse);
}

// Round 2
// 7540.926 us; speedup vs baseline: 1.9791x; 1.9791x over previous
//
#include <hip/hip_runtime.h>
#include <stdint.h>

typedef unsigned short u16;
typedef unsigned int u32;
typedef unsigned long long u64;

#define Hdim 512
#define Ddim 300
#define Tlen 1024
#define VG 40000
#define VS 25000
#define NGTOT (Tlen * VG)          // 40,960,000
#define NTOT  (Tlen * (VG + VS))   // 66,560,000

// ---- workspace layout (in floats; u64 arrays occupy 2 floats/elem) ----
#define F_XZ   0
#define F_XR   (F_XZ + Tlen * Hdim)
#define F_X1   (F_XR + Tlen * Hdim)
#define F_H1X  (F_X1 + Tlen * Hdim)            // u64[(Tlen+1)*512]
#define F_H2X  (F_H1X + (Tlen + 1) * Hdim * 2) // u64[(Tlen+1)*512]
#define F_R1X  (F_H2X + (Tlen + 1) * Hdim * 2) // u64[Tlen*512]
#define F_R2X  (F_R1X + Tlen * Hdim * 2)       // u64[Tlen*512]
#define F_HBF  (F_R2X + Tlen * Hdim * 2)       // u16[1024*512]
#define F_WGBF (F_HBF + (Tlen * Hdim) / 2)     // u16[512*40000]
#define F_WSBF (F_WGBF + (Hdim * VG) / 2)      // u16[512*25000]
#define F_PG   (F_WSBF + (Hdim * VS) / 2)      // [1024][625]
#define F_PS   (F_PG + Tlen * 625)             // [1024][391]
#define F_LSE  (F_PS + Tlen * 391)             // [2048]

__device__ __forceinline__ u16 f2bf(float f) {
    u32 u = __float_as_uint(f);
    u += 0x7fffu + ((u >> 16) & 1u);
    return (u16)(u >> 16);
}
__device__ __forceinline__ float bf2f(u16 s) { return __uint_as_float(((u32)s) << 16); }
__device__ __forceinline__ float sigm(float x) { return 1.f / (1.f + __expf(-x)); }

// tagged u64 exchange: {tag(step) in high32, f32 payload in low32}
__device__ __forceinline__ u64 pk(u32 tag, float v) {
    return ((u64)tag << 32) | (u64)__float_as_uint(v);
}
__device__ __forceinline__ float upf(u64 x) { return __uint_as_float((u32)x); }
__device__ __forceinline__ u32 uptag(u64 x) { return (u32)(x >> 32); }
__device__ __forceinline__ u64 ld64(const u64* p) {
    return __hip_atomic_load(p, __ATOMIC_RELAXED, __HIP_MEMORY_SCOPE_AGENT);
}
__device__ __forceinline__ void st64(u64* p, u64 v) {
    __hip_atomic_store(p, v, __ATOMIC_RELAXED, __HIP_MEMORY_SCOPE_AGENT);
}

// ---------------- init: seed h1x[0], h2x[0] with tag=1, val=0 ----------------
__global__ void k_init(u64* h1x, u64* h2x) {
    int i = blockIdx.x * 256 + threadIdx.x;
    if (i < Hdim) { h1x[i] = pk(1u, 0.f); h2x[i] = pk(1u, 0.f); }
}

// ---------------- x-projections: x_emb @ {Wz1,Wr1,W1} ----------------
__launch_bounds__(256)
__global__ void k_xproj(const int* tokens, const float* X,
                        const float* Wz1, const float* Wr1, const float* W1,
                        float* xz, float* xr, float* x1) {
    int tid = threadIdx.x;
    int jj = tid & 63, tg = tid >> 6;
    int mat = blockIdx.y >> 3;
    int j0 = (blockIdx.y & 7) * 64;
    int t0 = blockIdx.x * 16 + tg * 4;
    const float* W = (mat == 0) ? Wz1 : (mat == 1 ? Wr1 : W1);
    float* out = (mat == 0) ? xz : (mat == 1 ? xr : x1);
    const float* xrow[4];
#pragma unroll
    for (int u = 0; u < 4; ++u) xrow[u] = X + (size_t)tokens[t0 + u] * Ddim;
    float acc[4] = {0.f, 0.f, 0.f, 0.f};
    for (int k = 0; k < Ddim; ++k) {
        float w = W[(size_t)k * Hdim + j0 + jj];
#pragma unroll
        for (int u = 0; u < 4; ++u) acc[u] += xrow[u][k] * w;
    }
#pragma unroll
    for (int u = 0; u < 4; ++u) out[(size_t)(t0 + u) * Hdim + j0 + jj] = acc[u];
}

// ---------------- vocab weight fp32 -> bf16 ----------------
__global__ void k_wconv(const float* Wg, const float* Ws, u16* wgbf, u16* wsbf) {
    const int n4g = (Hdim * VG) / 4;
    const int n4s = (Hdim * VS) / 4;
    int stride = gridDim.x * blockDim.x;
    for (int i = blockIdx.x * blockDim.x + threadIdx.x; i < n4g + n4s; i += stride) {
        float4 v;
        u64* dst;
        if (i < n4g) { v = ((const float4*)Wg)[i]; dst = (u64*)wgbf + i; }
        else { int j = i - n4g; v = ((const float4*)Ws)[j]; dst = (u64*)wsbf + j; }
        u64 p = (u64)f2bf(v.x) | ((u64)f2bf(v.y) << 16) | ((u64)f2bf(v.z) << 32) | ((u64)f2bf(v.w) << 48);
        *dst = p;
    }
}

// ---------------- h2s -> bf16 (A matrix for GEMM) ----------------
__global__ void k_hbf(const u64* h2x, u16* hbf) {
    int i = blockIdx.x * 256 + threadIdx.x;   // 2048 x 256 == 524288
    hbf[i] = f2bf(upf(ld64(&h2x[i + Hdim]))); // h2s[t] = slot t+1
}

// ---------------- sequential GRU scan: 96 persistent WGs ----------------
#define G1n 32
#define C1n 16
#define G2n 64
#define C2n 8
#define WS 516   // LDS weight column stride (u16): 2-way max aliasing

__launch_bounds__(256)
__global__ void k_scan(const float* Uz1, const float* Ur1, const float* U1,
                       const float* Wz2, const float* Uz2, const float* Wr2,
                       const float* Ur2, const float* W2, const float* U2,
                       const float* xz, const float* xr, const float* x1,
                       u64* h1x, u64* h2x, u64* r1x, u64* r2x) {
    __shared__ u16 wsl[48 * WS];           // 48.4 KB weight slices (bf16)
    __shared__ float hA[Hdim], hB[Hdim], hC[Hdim];
    int tid = threadIdx.x;
    int g = blockIdx.x;

    if (g < G1n) {
        // ---------------- layer 1: 32 WGs x 16 output columns ----------------
        int c0 = g * C1n;
        const float* Us[3] = {Uz1, Ur1, U1};
        for (int m = 0; m < 3; ++m) {
            for (int k = 0; k < 2; ++k) {
                int i = tid + k * 256;
                const float* src = Us[m] + (size_t)i * Hdim + c0;
                float v[16];
#pragma unroll
                for (int q = 0; q < 4; ++q) {
                    float4 f = ((const float4*)src)[q];
                    v[q * 4] = f.x; v[q * 4 + 1] = f.y; v[q * 4 + 2] = f.z; v[q * 4 + 3] = f.w;
                }
#pragma unroll
                for (int cc = 0; cc < 16; ++cc) wsl[(m * C1n + cc) * WS + i] = f2bf(v[cc]);
            }
        }
        __syncthreads();
        int c = tid >> 4, r = tid & 15;
        const u16* wz = &wsl[(0 * C1n + c) * WS];
        const u16* wr = &wsl[(1 * C1n + c) * WS];
        const u16* w1 = &wsl[(2 * C1n + c) * WS];
        for (int t = 0; t < Tlen; ++t) {
            // prefetch x-projections (only r==0 lanes use them)
            float xzv = 0.f, xrv = 0.f, x1v = 0.f;
            if (r == 0) {
                xzv = xz[t * Hdim + c0 + c];
                xrv = xr[t * Hdim + c0 + c];
                x1v = x1[t * Hdim + c0 + c];
            }
            // ---- hop A: poll h1x[t] (tag t+1), tagged data -> hA ----
            {
                const u64* ph = h1x + (size_t)t * Hdim;
                u32 tg = (u32)(t + 1);
                u64 a0, a1;
                while (1) {
                    a0 = ld64(ph + tid); a1 = ld64(ph + tid + 256);
                    int ok = (uptag(a0) == tg) && (uptag(a1) == tg);
                    if (__syncthreads_and(ok)) break;
                }
                hA[tid] = upf(a0); hA[tid + 256] = upf(a1);
            }
            __syncthreads();
            // stage 1: z1, r1 (rotated LDS index: conflict-free)
            float az = 0.f, ar = 0.f;
#pragma unroll 8
            for (int ii = 0; ii < 32; ++ii) {
                int i = r * 32 + ((ii + r) & 31);
                float h = hA[i];
                az += h * bf2f(wz[i]);
                ar += h * bf2f(wr[i]);
            }
#pragma unroll
            for (int d = 8; d; d >>= 1) { az += __shfl_down(az, d, 16); ar += __shfl_down(ar, d, 16); }
            float zg = 0.f;
            if (r == 0) {
                zg = sigm(az + xzv);
                float rg = sigm(ar + xrv);
                st64(&r1x[(size_t)t * Hdim + c0 + c], pk((u32)(t + 1), rg));
            }
            // ---- hop B: poll r1x[t] -> hB ----
            {
                const u64* pr = r1x + (size_t)t * Hdim;
                u32 tg = (u32)(t + 1);
                u64 a0, a1;
                while (1) {
                    a0 = ld64(pr + tid); a1 = ld64(pr + tid + 256);
                    int ok = (uptag(a0) == tg) && (uptag(a1) == tg);
                    if (__syncthreads_and(ok)) break;
                }
                hB[tid] = upf(a0); hB[tid + 256] = upf(a1);
            }
            __syncthreads();
            // stage 2: candidate + h update
            float a = 0.f;
#pragma unroll 8
            for (int ii = 0; ii < 32; ++ii) {
                int i = r * 32 + ((ii + r) & 31);
                a += hB[i] * hA[i] * bf2f(w1[i]);
            }
#pragma unroll
            for (int d = 8; d; d >>= 1) a += __shfl_down(a, d, 16);
            if (r == 0) {
                float ht = tanhf(a + x1v);
                float hn = zg * ht + (1.f - zg) * hA[c0 + c];
                st64(&h1x[(size_t)(t + 1) * Hdim + c0 + c], pk((u32)(t + 2), hn));
            }
            __syncthreads();   // protect hA/hB before next step overwrites
        }
    } else {
        // ---------------- layer 2: 64 WGs x 8 output columns ----------------
        int g2 = g - G1n, c0 = g2 * C2n;
        const float* Us[6] = {Wz2, Uz2, Wr2, Ur2, W2, U2};
        for (int m = 0; m < 6; ++m) {
            for (int k = 0; k < 2; ++k) {
                int i = tid + k * 256;
                const float* src = Us[m] + (size_t)i * Hdim + c0;
                float v[8];
#pragma unroll
                for (int q = 0; q < 2; ++q) {
                    float4 f = ((const float4*)src)[q];
                    v[q * 4] = f.x; v[q * 4 + 1] = f.y; v[q * 4 + 2] = f.z; v[q * 4 + 3] = f.w;
                }
#pragma unroll
                for (int cc = 0; cc < 8; ++cc) wsl[(m * C2n + cc) * WS + i] = f2bf(v[cc]);
            }
        }
        __syncthreads();
        int c = tid >> 5, r = tid & 31;
        const u16* w0 = &wsl[(0 * C2n + c) * WS];
        const u16* w1p = &wsl[(1 * C2n + c) * WS];
        const u16* w2p = &wsl[(2 * C2n + c) * WS];
        const u16* w3p = &wsl[(3 * C2n + c) * WS];
        const u16* w4p = &wsl[(4 * C2n + c) * WS];
        const u16* w5p = &wsl[(5 * C2n + c) * WS];
        for (int t = 0; t < Tlen; ++t) {
            // ---- hop A: poll h1x[t+1] (tag t+2) and h2x[t] (tag t+1) ----
            {
                const u64* p1 = h1x + (size_t)(t + 1) * Hdim;
                const u64* p2 = h2x + (size_t)t * Hdim;
                u32 tg1 = (u32)(t + 2), tg2 = (u32)(t + 1);
                u64 a0, a1, b0, b1;
                while (1) {
                    a0 = ld64(p1 + tid); a1 = ld64(p1 + tid + 256);
                    b0 = ld64(p2 + tid); b1 = ld64(p2 + tid + 256);
                    int ok = (uptag(a0) == tg1) && (uptag(a1) == tg1) &&
                             (uptag(b0) == tg2) && (uptag(b1) == tg2);
                    if (__syncthreads_and(ok)) break;
                }
                hA[tid] = upf(a0); hA[tid + 256] = upf(a1);
                hB[tid] = upf(b0); hB[tid + 256] = upf(b1);
            }
            __syncthreads();
            // stage 1: z2, r2
            float az = 0.f, ar = 0.f;
#pragma unroll 8
            for (int ii = 0; ii < 16; ++ii) {
                int i = r * 16 + ((ii + r) & 15);
                float a_ = hA[i], b_ = hB[i];
                az += a_ * bf2f(w0[i]) + b_ * bf2f(w1p[i]);
                ar += a_ * bf2f(w2p[i]) + b_ * bf2f(w3p[i]);
            }
#pragma unroll
            for (int d = 16; d; d >>= 1) { az += __shfl_down(az, d, 32); ar += __shfl_down(ar, d, 32); }
            float zg = 0.f;
            if (r == 0) {
                zg = sigm(az);
                float rg = sigm(ar);
                st64(&r2x[(size_t)t * Hdim + c0 + c], pk((u32)(t + 1), rg));
            }
            // ---- hop B: poll r2x[t] -> hC ----
            {
                const u64* pr = r2x + (size_t)t * Hdim;
                u32 tg = (u32)(t + 1);
                u64 a0, a1;
                while (1) {
                    a0 = ld64(pr + tid); a1 = ld64(pr + tid + 256);
                    int ok = (uptag(a0) == tg) && (uptag(a1) == tg);
                    if (__syncthreads_and(ok)) break;
                }
                hC[tid] = upf(a0); hC[tid + 256] = upf(a1);
            }
            __syncthreads();
            // stage 2: candidate + h update
            float a = 0.f;
#pragma unroll 8
            for (int ii = 0; ii < 16; ++ii) {
                int i = r * 16 + ((ii + r) & 15);
                a += hA[i] * bf2f(w4p[i]) + hC[i] * hB[i] * bf2f(w5p[i]);
            }
#pragma unroll
            for (int d = 16; d; d >>= 1) a += __shfl_down(a, d, 32);
            if (r == 0) {
                float ht = tanhf(a);
                float hn = zg * ht + (1.f - zg) * hB[c0 + c];
                st64(&h2x[(size_t)(t + 1) * Hdim + c0 + c], pk((u32)(t + 2), hn));
            }
            __syncthreads();
        }
    }
}

// ---------------- bf16 MFMA GEMM: logits + per-block sumexp partials ----------------
typedef __attribute__((ext_vector_type(8))) short bfrag;
typedef __attribute__((ext_vector_type(4))) float f32x4;

__launch_bounds__(256)
__global__ void k_gemm(const u16* A, const u16* B, const float* bias,
                       float* out, float* partial, int N, int nblk) {
    __shared__ u16 As[64 * 40];
    __shared__ u16 Bs[64 * 40];
    int tid = threadIdx.x, lane = tid & 63, wid = tid >> 6;
    int m0 = blockIdx.x * 64, n0 = blockIdx.y * 64;
    f32x4 acc[4] = {{0.f, 0.f, 0.f, 0.f}, {0.f, 0.f, 0.f, 0.f}, {0.f, 0.f, 0.f, 0.f}, {0.f, 0.f, 0.f, 0.f}};
    int arow = tid >> 2, akc = (tid & 3) * 8;
    int bkr = tid >> 3, bnc = (tid & 7) * 8;
    bool bvalid = (n0 + bnc) < N;
    int lm = lane & 15, q = lane >> 4;
    for (int kt = 0; kt < 16; ++kt) {
        int k0 = kt * 32;
        uint4 av = *(const uint4*)(A + (size_t)(m0 + arow) * Hdim + k0 + akc);
        *((uint4*)&As[arow * 40 + akc]) = av;
        union { uint4 v; u16 s[8]; } ub;
        ub.v = make_uint4(0, 0, 0, 0);
        if (bvalid) ub.v = *(const uint4*)(B + (size_t)(k0 + bkr) * N + n0 + bnc);
#pragma unroll
        for (int j = 0; j < 8; ++j) Bs[(bnc + j) * 40 + bkr] = ub.s[j];
        __syncthreads();
        bfrag af = *(const bfrag*)&As[(wid * 16 + lm) * 40 + q * 8];
#pragma unroll
        for (int ns = 0; ns < 4; ++ns) {
            bfrag bf_ = *(const bfrag*)&Bs[(ns * 16 + lm) * 40 + q * 8];
            acc[ns] = __builtin_amdgcn_mfma_f32_16x16x32_bf16(af, bf_, acc[ns], 0, 0, 0);
        }
        __syncthreads();
    }
    float rs[4] = {0.f, 0.f, 0.f, 0.f};
#pragma unroll
    for (int ns = 0; ns < 4; ++ns) {
        int col = n0 + ns * 16 + lm;
        bool cv = col < N;
        float bi = cv ? bias[col] : 0.f;
#pragma unroll
        for (int rr = 0; rr < 4; ++rr) {
            int row = wid * 16 + q * 4 + rr;
            float v = acc[ns][rr] + bi;
            if (cv) {
                out[(size_t)(m0 + row) * N + col] = v;
                rs[rr] += __expf(v);
            }
        }
    }
#pragma unroll
    for (int rr = 0; rr < 4; ++rr) {
#pragma unroll
        for (int d = 1; d < 16; d <<= 1) rs[rr] += __shfl_xor(rs[rr], d, 64);
    }
    if (lm == 0) {
#pragma unroll
        for (int rr = 0; rr < 4; ++rr) {
            int row = wid * 16 + q * 4 + rr;
            partial[(size_t)(m0 + row) * nblk + blockIdx.y] = rs[rr];
        }
    }
}

// ---------------- per-row logsumexp reduce ----------------
__global__ void k_lse(const float* pG, const float* pS, float* lse) {
    int row = blockIdx.x;
    int tid = threadIdx.x;
    const float* p;
    int nb;
    if (row < Tlen) { p = pG + (size_t)row * 625; nb = 625; }
    else { p = pS + (size_t)(row - Tlen) * 391; nb = 391; }
    float s = 0.f;
    for (int j = tid; j < nb; j += 256) s += p[j];
#pragma unroll
    for (int d = 32; d; d >>= 1) s += __shfl_down(s, d, 64);
    __shared__ float red[4];
    if ((tid & 63) == 0) red[tid >> 6] = s;
    __syncthreads();
    if (tid == 0) lse[row] = logf(red[0] + red[1] + red[2] + red[3]);
}

// ---------------- in-place fixup: out -= lse[row] ----------------
__global__ void k_fix(float* out, const float* lse) {
    const size_t n4 = NTOT / 4;
    size_t stride = (size_t)gridDim.x * blockDim.x;
    for (size_t i = (size_t)blockIdx.x * blockDim.x + threadIdx.x; i < n4; i += stride) {
        size_t e = i * 4;
        float l;
        if (e < (size_t)NGTOT) l = lse[e / VG];
        else l = lse[Tlen + (e - (size_t)NGTOT) / VS];
        float4 v = ((float4*)out)[i];
        v.x -= l; v.y -= l; v.z -= l; v.w -= l;
        ((float4*)out)[i] = v;
    }
}

extern "C" void kernel_launch(void* const* d_in, const int* in_sizes, int n_in,
                              void* d_out, int out_size, void* d_ws, size_t ws_size,
                              hipStream_t stream) {
    const int* tokens = (const int*)d_in[0];
    const float* X   = (const float*)d_in[1];
    const float* Wz1 = (const float*)d_in[2];
    const float* Uz1 = (const float*)d_in[3];
    const float* Wr1 = (const float*)d_in[4];
    const float* Ur1 = (const float*)d_in[5];
    const float* W1  = (const float*)d_in[6];
    const float* U1  = (const float*)d_in[7];
    const float* Wz2 = (const float*)d_in[8];
    const float* Uz2 = (const float*)d_in[9];
    const float* Wr2 = (const float*)d_in[10];
    const float* Ur2 = (const float*)d_in[11];
    const float* W2  = (const float*)d_in[12];
    const float* U2  = (const float*)d_in[13];
    const float* Wg  = (const float*)d_in[14];
    const float* bg  = (const float*)d_in[15];
    const float* Ws  = (const float*)d_in[16];
    const float* bs  = (const float*)d_in[17];

    float* wsf = (float*)d_ws;
    float* xz = wsf + F_XZ;
    float* xr = wsf + F_XR;
    float* x1 = wsf + F_X1;
    u64* h1x = (u64*)(wsf + F_H1X);
    u64* h2x = (u64*)(wsf + F_H2X);
    u64* r1x = (u64*)(wsf + F_R1X);
    u64* r2x = (u64*)(wsf + F_R2X);
    u16* hbf  = (u16*)(wsf + F_HBF);
    u16* wgbf = (u16*)(wsf + F_WGBF);
    u16* wsbf = (u16*)(wsf + F_WSBF);
    float* pG = wsf + F_PG;
    float* pS = wsf + F_PS;
    float* lse = wsf + F_LSE;
    float* outF = (float*)d_out;

    hipLaunchKernelGGL(k_init, dim3(2), dim3(256), 0, stream, h1x, h2x);
    hipLaunchKernelGGL(k_xproj, dim3(64, 24), dim3(256), 0, stream,
                       tokens, X, Wz1, Wr1, W1, xz, xr, x1);
    hipLaunchKernelGGL(k_wconv, dim3(4096), dim3(256), 0, stream, Wg, Ws, wgbf, wsbf);
    hipLaunchKernelGGL(k_scan, dim3(96), dim3(256), 0, stream,
                       Uz1, Ur1, U1, Wz2, Uz2, Wr2, Ur2, W2, U2,
                       xz, xr, x1, h1x, h2x, r1x, r2x);
    hipLaunchKernelGGL(k_hbf, dim3(2048), dim3(256), 0, stream, h2x, hbf);
    hipLaunchKernelGGL(k_gemm, dim3(16, 625), dim3(256), 0, stream,
                       hbf, wgbf, bg, outF, pG, VG, 625);
    hipLaunchKernelGGL(k_gemm, dim3(16, 391), dim3(256), 0, stream,
                       hbf, wsbf, bs, outF + (size_t)NGTOT, pS, VS, 391);
    hipLaunchKernelGGL(k_lse, dim3(2048), dim3(256), 0, stream, pG, pS, lse);
    hipLaunchKernelGGL(k_fix, dim3(8192), dim3(256), 0, stream, outF, lse);
}